// Round 1
// baseline (988.083 us; speedup 1.0000x reference)
//
#include <hip/hip_runtime.h>
#include <cmath>

// GNN fused kernel: B=1e6 nodes, C=3 channels, K=64 neighbors.
//   h[c]   = tanh(Ws[c,:]·x + bs[c])
//   pooled = mean_k neighbors[:, k]
//   z[o]   = sum_c Wc[o,c,0]*h[c] + Wc[o,c,1]*pooled[c] + bc[o]
//   out    = tanh(tanh(z))
// Memory-bound: neighbors = 768 MB read-once dominates. Layout (B,C,K) means
// each node owns 192 contiguous floats = 48 float4s. Block = 192 threads
// (3 waves) = 4 nodes = 192 float4s, thread t loads float4 (block*192 + t):
// perfectly coalesced. Each (node,channel) = 16 consecutive float4s = one
// 16-lane shuffle-reduce group (16 | 64, never straddles a wave).

#define THREADS 192
#define NODES_PER_BLOCK 4

__global__ __launch_bounds__(THREADS) void gnn_fused_kernel(
    const float* __restrict__ x,       // [B,3,1]
    const float4* __restrict__ nbr,    // [B,3,64] viewed as float4
    const float* __restrict__ Ws,      // [3,3]
    const float* __restrict__ bs,      // [3]
    const float* __restrict__ Wc,      // [3,3,2]
    const float* __restrict__ bc,      // [3]
    float* __restrict__ out,           // [B,3,1]
    long long num_nodes)
{
    __shared__ float pooled[NODES_PER_BLOCK * 3];  // [node][channel]

    const int t = threadIdx.x;
    const long long gf = (long long)blockIdx.x * THREADS + t;  // global float4 idx
    const long long total_f4 = num_nodes * 48;

    float s = 0.0f;
    if (gf < total_f4) {
        float4 v = nbr[gf];
        s = (v.x + v.y) + (v.z + v.w);
    }
    // reduce the 16 lanes that share one (node, channel)
    s += __shfl_xor(s, 1);
    s += __shfl_xor(s, 2);
    s += __shfl_xor(s, 4);
    s += __shfl_xor(s, 8);
    if ((t & 15) == 0) pooled[t >> 4] = s * (1.0f / 64.0f);
    __syncthreads();

    if (t < NODES_PER_BLOCK * 3) {
        const int n = t / 3;   // node within block
        const int o = t % 3;   // output channel
        const long long node = (long long)blockIdx.x * NODES_PER_BLOCK + n;
        if (node < num_nodes) {
            const float* xp = x + node * 3;
            const float x0 = xp[0], x1 = xp[1], x2 = xp[2];
            float z = bc[o];
#pragma unroll
            for (int c = 0; c < 3; ++c) {
                float h = tanhf(Ws[c * 3 + 0] * x0 + Ws[c * 3 + 1] * x1 +
                                Ws[c * 3 + 2] * x2 + bs[c]);
                z += Wc[o * 6 + c * 2 + 0] * h +
                     Wc[o * 6 + c * 2 + 1] * pooled[n * 3 + c];
            }
            out[node * 3 + o] = tanhf(tanhf(z));
        }
    }
}

extern "C" void kernel_launch(void* const* d_in, const int* in_sizes, int n_in,
                              void* d_out, int out_size, void* d_ws, size_t ws_size,
                              hipStream_t stream) {
    const float*  x   = (const float*)d_in[0];
    const float4* nbr = (const float4*)d_in[1];
    const float*  Ws  = (const float*)d_in[2];
    const float*  bs  = (const float*)d_in[3];
    const float*  Wc  = (const float*)d_in[4];
    const float*  bc  = (const float*)d_in[5];
    float* out = (float*)d_out;

    const long long num_nodes = (long long)in_sizes[0] / 3;  // x is [B,3,1]
    const long long blocks = (num_nodes + NODES_PER_BLOCK - 1) / NODES_PER_BLOCK;

    gnn_fused_kernel<<<(unsigned)blocks, THREADS, 0, stream>>>(
        x, nbr, Ws, bs, Wc, bc, out, num_nodes);
}